// Round 20
// baseline (150.445 us; speedup 1.0000x reference)
//
#include <hip/hip_runtime.h>
#include <cstdint>

// XLA emits separate mul/add; contraction off by default. Hot paths use
// explicit fmaf()/hw-transcendentals — measured-safe across 16 rounds
// (absmax pinned at 3.36e7 vs threshold 4.76e34 for r8-r19's variants).
#pragma clang fp contract(off)

#define TSAVES 49
#define SPSAVE 100
#define NB 8192
#define TRAJ 32                    // trajectories per block
#define GENW 15                    // noise-generator waves per block
#define NDEPTH 8                   // noise ring depth (gen run-ahead)

// Per-wave gen-unit counts, nibble-packed, w0 in low nibble. SIMD s hosts
// waves {s, s+4, s+8, s+12}: S0 {0,4,8,12}=4+4+3+3=14, S1 {1,5,9,13}=14,
// S2 {2,6,10,14}=4+4+3+3=14, S3 {3,7,11}=3+3+2=8 (+ merged sim wave 15).
// r19 lesson: S3 (13 units + si) was the critical SIMD; merging r0+si into
// one wave and giving S3 only 8 units levels all four SIMDs at ~2700-2850 cy.
#define CNTPACK 0x333233334443444ULL

typedef float f32x4 __attribute__((ext_vector_type(4)));

__device__ __forceinline__ uint32_t rotl32(uint32_t v, int d) {
  return __builtin_rotateleft32(v, (uint32_t)d);
}

// JAX threefry2x32, 20 rounds.
__device__ __forceinline__ void tf2x32(uint32_t k0, uint32_t k1,
                                       uint32_t x0, uint32_t x1,
                                       uint32_t& o0, uint32_t& o1) {
  uint32_t ks2 = k0 ^ k1 ^ 0x1BD11BDAu;
#define TF_ROUND(r) { x0 += x1; x1 = rotl32(x1, r); x1 ^= x0; }
  x0 += k0; x1 += k1;
  TF_ROUND(13) TF_ROUND(15) TF_ROUND(26) TF_ROUND(6)
  x0 += k1; x1 += ks2 + 1u;
  TF_ROUND(17) TF_ROUND(29) TF_ROUND(16) TF_ROUND(24)
  x0 += ks2; x1 += k0 + 2u;
  TF_ROUND(13) TF_ROUND(15) TF_ROUND(26) TF_ROUND(6)
  x0 += k0; x1 += k1 + 3u;
  TF_ROUND(17) TF_ROUND(29) TF_ROUND(16) TF_ROUND(24)
  x0 += k1; x1 += ks2 + 4u;
  TF_ROUND(13) TF_ROUND(15) TF_ROUND(26) TF_ROUND(6)
  x0 += ks2; x1 += k0 + 5u;
#undef TF_ROUND
  o0 = x0; o1 = x1;
}

// jax.random.split(key(seed)), jax_threefry_partitionable=True (fold-like).
__device__ __forceinline__ void derive_keys(int seed, uint32_t& kn0, uint32_t& kn1,
                                            uint32_t& ku0, uint32_t& ku1) {
  uint64_t sv = (uint64_t)(int64_t)seed;
  uint32_t k0 = (uint32_t)(sv >> 32);
  uint32_t k1 = (uint32_t)(sv & 0xffffffffULL);
  tf2x32(k0, k1, 0u, 0u, kn0, kn1);  // keys[0] = k_noise
  tf2x32(k0, k1, 0u, 1u, ku0, ku1);  // keys[1] = k_u
}

// partitionable random_bits(32): counter = (hi=0, lo=n); bits = y0 ^ y1.
__device__ __forceinline__ uint32_t rand_bits32(uint32_t k0, uint32_t k1, uint32_t n) {
  uint32_t y0, y1;
  tf2x32(k0, k1, 0u, n, y0, y1);
  return y0 ^ y1;
}

// bits -> erfinv-core p*u (XLA ErfInv32/Giles). Caller multiplies by
// cpv = (0.1*sqrt(2))*pvol — validated bit-compatible since r8.
__device__ __forceinline__ float bits_to_eu(uint32_t bits) {
#pragma clang fp contract(fast)
  float u01 = __uint_as_float((bits >> 9) | 0x3f800000u) - 1.0f;
  float u = u01 * 2.0f + (-0.99999994f);
  u = fmaxf(-0.99999994f, u);
  float omu2 = 1.0f - u * u;                       // fma(-u,u,1)
  float w = -(__builtin_amdgcn_logf(omu2) * 0.6931472f);  // v_log (log2) * ln2
  float p;
  if (w < 5.0f) {
    float z = w - 2.5f;
    p = 2.81022636e-08f;
    p = 3.43273939e-07f + p * z;
    p = -3.5233877e-06f + p * z;
    p = -4.39150654e-06f + p * z;
    p = 0.00021858087f + p * z;
    p = -0.00125372503f + p * z;
    p = -0.00417768164f + p * z;
    p = 0.246640727f + p * z;
    p = 1.50140941f + p * z;
  } else {
    float z = __builtin_amdgcn_sqrtf(w) - 3.0f;
    p = -0.000200214257f;
    p = 0.000100950558f + p * z;
    p = 0.00134934322f + p * z;
    p = -0.00367342844f + p * z;
    p = 0.00573950773f + p * z;
    p = -0.0076224613f + p * z;
    p = 0.00943887047f + p * z;
    p = 1.00167406f + p * z;
    p = 2.83297682f + p * z;
  }
  return p * u;
}

__device__ __forceinline__ float clip_param(float x) {
  return fminf(0.99999988f, fmaxf(1e-07f, x));
}

// Fused, barrier-free: 256 blocks x 16 waves = 15 gen + 1 MERGED sim wave
// (r0 chain + s,i + summarize in one wave — entering-r0 passes in registers,
// rbuf eliminated, one producer->consumer sync edge). Gen fills an 8-deep
// LDS noise ring; monotone counters + s_sleep spins (r15/r17/r19-validated).
__global__ __launch_bounds__(1024) void fused_kernel(const float* __restrict__ cond,
                                                     const int* __restrict__ seedp,
                                                     float* __restrict__ out) {
  __shared__ f32x4 nbuf[NDEPTH][25][TRAJ];  // 102.4 KiB noise ring
  __shared__ int done[TSAVES];              // gen waves finished with group g (of 15)
  __shared__ int simcnt;

  const int tid = threadIdx.x;
  const int lane = tid & 63;
  const int wv = tid >> 6;
  const int bbase = blockIdx.x * TRAJ;
  const int tr = lane & 31;
  const int h = lane >> 5;              // gen: e-parity selector
  const int b = bbase + tr;

  if (tid < TSAVES) done[tid] = 0;
  if (tid == 0) simcnt = 0;
  __syncthreads();

  volatile int* vdone = done;
  volatile int* vsim = &simcnt;

  uint32_t kn0, kn1, ku0, ku1;
  derive_keys(seedp[0], kn0, kn1, ku0, ku1);

  float pinf = clip_param(cond[b * 4 + 0]);
  float prec = clip_param(cond[b * 4 + 1]);
  float pmr  = clip_param(cond[b * 4 + 2]);
  float pvol = clip_param(cond[b * 4 + 3]);
  const float r0m  = pinf / prec;
  const float dtmr = 0.01f * pmr;
  const float c4 = 1.0f - dtmr;
  const float a4 = dtmr * r0m;
  const float c2 = 0.01f * prec;
  const float c3 = 1.0f - c2;
  const float c3p4 = (c3 * c3) * (c3 * c3);
  const float cpv = 0.14142136f * pvol;     // 0.1*sqrt(2) folded (r8+)

  if (wv < GENW) {
    // -------- producers: rebalanced static units (see CNTPACK) --------
    const int cnt = (int)((CNTPACK >> (4 * wv)) & 0xFULL);
    int off = 0;
#pragma unroll
    for (int w = 0; w < GENW; ++w) if (w < wv) off += (int)((CNTPACK >> (4 * w)) & 0xFULL);
    for (int g = 0; g <= 48; ++g) {
      if (g >= NDEPTH) {                   // ring slot free when sim did g-NDEPTH
        while (*vsim < g - (NDEPTH - 1)) __builtin_amdgcn_s_sleep(1);
      }
      const uint32_t nbase = (uint32_t)(g * SPSAVE) * (uint32_t)NB + (uint32_t)b;
      float* nb = (float*)&nbuf[g % NDEPTH][0][0];
      for (int k = 0; k < cnt; ++k) {
        const int id = off + k;            // 0..49 chunk-halves
        const int c = id >> 1;
        const int e = ((id & 1) << 1) | h;
        uint32_t n = nbase + (uint32_t)(4 * c + e) * (uint32_t)NB;
        float eu = bits_to_eu(rand_bits32(kn0, kn1, n));
        nb[(c * 32 + tr) * 4 + e] = eu * cpv;
      }
      __threadfence_block();               // drain ds_writes before signaling
      if (lane == 0) atomicAdd(&done[g], 1);
    }
  } else {
    // -------- merged sim: r0 chain + s,i + summarize (one wave) --------
    float r0 = r0m;
    float s = 0.99f, i = 0.01f;
    float best = -1.0f; int bi = 0;
    float plg = 0.0f, sd = 0.0f, sd2 = 0.0f;
    for (int g = 0; g <= 48; ++g) {
      while (vdone[g] < GENW) __builtin_amdgcn_s_sleep(1);
      __threadfence_block();               // acquire
      const int sn = g % NDEPTH;
      f32x4 vd = nbuf[sn][0][tr];
#pragma unroll
      for (int c = 0; c < 25; ++c) {
        f32x4 vdn = (c < 24) ? nbuf[sn][c + 1][tr] : vd;  // prefetch next
        // 4 chain steps, capturing entering-r0 values in registers
        float e0 = r0;
        { float sq = __builtin_amdgcn_sqrtf(fabsf(r0));
          float r0h = fmaf(c4, r0, a4); r0 = fmaf(sq, vd[0], r0h); }
        float e1 = r0;
        { float sq = __builtin_amdgcn_sqrtf(fabsf(r0));
          float r0h = fmaf(c4, r0, a4); r0 = fmaf(sq, vd[1], r0h); }
        float e2 = r0;
        { float sq = __builtin_amdgcn_sqrtf(fabsf(r0));
          float r0h = fmaf(c4, r0, a4); r0 = fmaf(sq, vd[2], r0h); }
        float e3 = r0;
        { float sq = __builtin_amdgcn_sqrtf(fabsf(r0));
          float r0h = fmaf(c4, r0, a4); r0 = fmaf(sq, vd[3], r0h); }
        // s,i — exact r12-r19 op order (entering values e0..e3)
        float rs0 = e0 * s; s = fmaf(-c2, rs0, s);
        float rs1 = e1 * s; s = fmaf(-c2, rs1, s);
        float rs2 = e2 * s; s = fmaf(-c2, rs2, s);
        float rs3 = e3 * s; s = fmaf(-c2, rs3, s);
        float hh = fmaf(c3, rs0, rs1);
        hh = fmaf(c3, hh, rs2);
        hh = fmaf(c3, hh, rs3);
        i = fmaf(c3p4, i, c2 * hh);
        vd = vdn;
      }
      float v = i;
      if (!isfinite(v)) v = 0.0f;
      float x = fmaxf(v, 1e-05f);
      if (x > best) { best = x; bi = g; }
      float lg = __builtin_amdgcn_logf(x) * 0.6931472f;
      if (g > 0) { float d = lg - plg; sd += d; sd2 += d * d; }
      plg = lg;
      __threadfence_block();               // reads retired before release
      if (lane == 0) *vsim = g + 1;
    }
    if (lane < TRAJ) {
      uint32_t ub = rand_bits32(ku0, ku1, (uint32_t)b);
      float u = __uint_as_float((ub >> 9) | 0x3f800000u) - 1.0f;
      u = fmaxf(0.0f, u);
      float maxat = ((float)bi + u) / 49.0f;
      float mean = sd / 48.0f;
      float var = sd2 / 48.0f - mean * mean;
      float stdv = sqrtf(fmaxf(var, 0.0f));
      out[b * 3 + 0] = (best  - 0.38f) / 0.14f;
      out[b * 3 + 1] = (maxat - 0.21f) / 0.12f;
      out[b * 3 + 2] = (stdv  - 0.14f) / 0.03f;
    }
  }
}

extern "C" void kernel_launch(void* const* d_in, const int* in_sizes, int n_in,
                              void* d_out, int out_size, void* d_ws, size_t ws_size,
                              hipStream_t stream) {
  const float* cond = (const float*)d_in[0];
  const int* seedp = (const int*)d_in[1];
  float* out = (float*)d_out;
  (void)d_ws; (void)ws_size;   // fully LDS-resident: no workspace needed
  fused_kernel<<<NB / TRAJ, 1024, 0, stream>>>(cond, seedp, out);
}